// Round 1
// baseline (386.042 us; speedup 1.0000x reference)
//
#include <hip/hip_runtime.h>

#define H 4
#define NQ 4096
#define NK 8192
#define D 64
#define E 256
#define BK 64
#define LDK 72

typedef short v8s __attribute__((ext_vector_type(8)));
typedef float v4f __attribute__((ext_vector_type(4)));

static __device__ __forceinline__ unsigned short f2bf(float f) {
    unsigned int u = __float_as_uint(f);
    u = (u + 0x7FFFu + ((u >> 16) & 1u)) >> 16;
    return (unsigned short)u;
}

// ---- Q projection + RoPE + 1/sqrt(D) scale -> bf16 [H][NQ][D]
__global__ __launch_bounds__(256) void qproj_kernel(
    const float* __restrict__ query, const float* __restrict__ Wq,
    const float* __restrict__ bq, unsigned short* __restrict__ Qb)
{
    const int n0 = blockIdx.x * 16;
    const int i = threadIdx.x;
    float acc[16];
    const float b = bq[i];
#pragma unroll
    for (int r = 0; r < 16; ++r) acc[r] = b;
#pragma unroll 4
    for (int e = 0; e < E; ++e) {
        const float w = Wq[e * 256 + i];
#pragma unroll
        for (int r = 0; r < 16; ++r)
            acc[r] = fmaf(query[(n0 + r) * 256 + e], w, acc[r]);
    }
    const int d = i & 63, h = i >> 6;
    const int j = d >> 1;
    const float freq = exp2f(-(float)(j & 15) * 1.66096404744368f); // 10000^(-(j%16)/8)
    const bool isx = (j < 16);
    const bool odd = (d & 1);
#pragma unroll
    for (int r = 0; r < 16; ++r) {
        const int p = n0 + r;
        const float tpos = isx ? (float)(p & 63) : (float)(p >> 6);
        const float ang = tpos * freq;
        const float c = cosf(ang), s = sinf(ang);
        const float x = acc[r];
        const float xp = __shfl_xor(x, 1, 64);
        float y = odd ? fmaf(x, c, xp * s) : fmaf(x, c, -xp * s);
        y *= 0.125f;
        Qb[(h * NQ + p) * D + d] = f2bf(y);
    }
}

// ---- K projection + conditional RoPE -> bf16 [H][NK][D]
__global__ __launch_bounds__(256) void kproj_kernel(
    const float* __restrict__ key, const float* __restrict__ Wk,
    const float* __restrict__ bk, unsigned short* __restrict__ Kb,
    const int* __restrict__ nexp)
{
    const int n0 = blockIdx.x * 32;
    const int i = threadIdx.x;
    const int nro = NK - *nexp; // rope applies to p < nro
    float acc[32];
    const float b = bk[i];
#pragma unroll
    for (int r = 0; r < 32; ++r) acc[r] = b;
#pragma unroll 4
    for (int e = 0; e < 64; ++e) {
        const float w = Wk[e * 256 + i];
#pragma unroll
        for (int r = 0; r < 32; ++r)
            acc[r] = fmaf(key[(n0 + r) * 64 + e], w, acc[r]);
    }
    const int d = i & 63, h = i >> 6;
    const int j = d >> 1;
    const float freq = exp2f(-(float)(j & 15) * 1.66096404744368f);
    const bool isx = (j < 16);
    const bool odd = (d & 1);
#pragma unroll
    for (int r = 0; r < 32; ++r) {
        const int p = n0 + r;
        const int pc = p & 4095; // cache tiled with repeats
        const float tpos = isx ? (float)(pc & 63) : (float)(pc >> 6);
        const float ang = tpos * freq;
        const float c = cosf(ang), s = sinf(ang);
        const float x = acc[r];
        const float xp = __shfl_xor(x, 1, 64);
        const float yr = odd ? fmaf(x, c, xp * s) : fmaf(x, c, -xp * s);
        const float y = (p < nro) ? yr : x;
        Kb[(h * NK + p) * D + d] = f2bf(y);
    }
}

// ---- V projection -> bf16 TRANSPOSED [H][D][NK]
__global__ __launch_bounds__(256) void vproj_kernel(
    const float* __restrict__ value, const float* __restrict__ Wv,
    const float* __restrict__ bv, unsigned short* __restrict__ Vt)
{
    const int n0 = blockIdx.x * 32;
    const int i = threadIdx.x;
    float acc[32];
    const float b = bv[i];
#pragma unroll
    for (int r = 0; r < 32; ++r) acc[r] = b;
#pragma unroll 4
    for (int e = 0; e < 64; ++e) {
        const float w = Wv[e * 256 + i];
#pragma unroll
        for (int r = 0; r < 32; ++r)
            acc[r] = fmaf(value[(n0 + r) * 64 + e], w, acc[r]);
    }
    const int d = i & 63, h = i >> 6;
    unsigned int buf[16];
#pragma unroll
    for (int m = 0; m < 16; ++m)
        buf[m] = (unsigned int)f2bf(acc[2 * m]) | ((unsigned int)f2bf(acc[2 * m + 1]) << 16);
    unsigned short* dst = Vt + (size_t)(h * D + d) * NK + n0;
#pragma unroll
    for (int g = 0; g < 4; ++g) {
        uint4 t4;
        t4.x = buf[4 * g]; t4.y = buf[4 * g + 1]; t4.z = buf[4 * g + 2]; t4.w = buf[4 * g + 3];
        *(uint4*)(dst + g * 8) = t4;
    }
}

// ---- flash attention: 256 blocks = 4 heads x 64 q-tiles(64 rows); 4 waves x M=16
__global__ __launch_bounds__(256) void attn_kernel(
    const unsigned short* __restrict__ Qb, const unsigned short* __restrict__ Kb,
    const unsigned short* __restrict__ Vt, float* __restrict__ Oout)
{
    __shared__ alignas(16) unsigned short Kl[BK * LDK];
    __shared__ alignas(16) unsigned short Vl[D * LDK];
    __shared__ alignas(16) unsigned short Pl[4 * 16 * LDK];

    const int h = blockIdx.x >> 6;
    const int qt = blockIdx.x & 63;
    const int t = threadIdx.x;
    const int w = t >> 6, lane = t & 63;
    const int quad = lane >> 4, l16 = lane & 15;

    const int q0 = qt * 64 + w * 16;
    const unsigned short* qrow = Qb + (size_t)(h * NQ + q0 + l16) * D;
    const v8s a0 = *(const v8s*)(qrow + quad * 8);
    const v8s a1 = *(const v8s*)(qrow + 32 + quad * 8);

    v4f Ofr[4];
#pragma unroll
    for (int dt = 0; dt < 4; ++dt) Ofr[dt] = v4f{0.f, 0.f, 0.f, 0.f};
    float m_r[4], l_r[4];
#pragma unroll
    for (int r = 0; r < 4; ++r) { m_r[r] = -1e30f; l_r[r] = 0.f; }

    unsigned short* Pw = &Pl[w * 16 * LDK];

    for (int k0 = 0; k0 < NK; k0 += BK) {
        __syncthreads();
#pragma unroll
        for (int it = 0; it < 2; ++it) {
            const int s = t + it * 256;
            const int row = s >> 3, seg = s & 7;
            *(uint4*)(&Kl[row * LDK + seg * 8]) =
                *(const uint4*)(Kb + (size_t)(h * NK + k0 + row) * D + seg * 8);
            *(uint4*)(&Vl[row * LDK + seg * 8]) =
                *(const uint4*)(Vt + (size_t)(h * D + row) * NK + k0 + seg * 8);
        }
        __syncthreads();

        // S = Q K^T : 4 tiles of 16 k-positions
        v4f S[4];
#pragma unroll
        for (int tt = 0; tt < 4; ++tt) {
            const v8s b0 = *(const v8s*)(&Kl[(tt * 16 + l16) * LDK + quad * 8]);
            const v8s b1 = *(const v8s*)(&Kl[(tt * 16 + l16) * LDK + 32 + quad * 8]);
            v4f acc = v4f{0.f, 0.f, 0.f, 0.f};
            acc = __builtin_amdgcn_mfma_f32_16x16x32_bf16(a0, b0, acc, 0, 0, 0);
            acc = __builtin_amdgcn_mfma_f32_16x16x32_bf16(a1, b1, acc, 0, 0, 0);
            S[tt] = acc;
        }

        // online softmax (rows = quad*4+r)
        float alpha[4];
#pragma unroll
        for (int r = 0; r < 4; ++r) {
            float v = fmaxf(fmaxf(S[0][r], S[1][r]), fmaxf(S[2][r], S[3][r]));
            v = fmaxf(v, __shfl_xor(v, 1, 64));
            v = fmaxf(v, __shfl_xor(v, 2, 64));
            v = fmaxf(v, __shfl_xor(v, 4, 64));
            v = fmaxf(v, __shfl_xor(v, 8, 64));
            const float mnew = fmaxf(m_r[r], v);
            alpha[r] = __expf(m_r[r] - mnew);
            m_r[r] = mnew;
        }
        float psum[4] = {0.f, 0.f, 0.f, 0.f};
#pragma unroll
        for (int tt = 0; tt < 4; ++tt) {
#pragma unroll
            for (int r = 0; r < 4; ++r) {
                const float e = __expf(S[tt][r] - m_r[r]);
                psum[r] += e;
                Pw[(quad * 4 + r) * LDK + tt * 16 + l16] = f2bf(e);
            }
        }
#pragma unroll
        for (int r = 0; r < 4; ++r) {
            float v = psum[r];
            v += __shfl_xor(v, 1, 64);
            v += __shfl_xor(v, 2, 64);
            v += __shfl_xor(v, 4, 64);
            v += __shfl_xor(v, 8, 64);
            l_r[r] = l_r[r] * alpha[r] + v;
#pragma unroll
            for (int dt = 0; dt < 4; ++dt) Ofr[dt][r] *= alpha[r];
        }
        __asm__ volatile("s_waitcnt lgkmcnt(0)" ::: "memory");
        // P (A-layout) from per-wave LDS; V (B-layout) from transposed LDS
        const v8s p0 = *(const v8s*)(&Pw[l16 * LDK + quad * 8]);
        const v8s p1 = *(const v8s*)(&Pw[l16 * LDK + 32 + quad * 8]);
#pragma unroll
        for (int dt = 0; dt < 4; ++dt) {
            const v8s v0 = *(const v8s*)(&Vl[(dt * 16 + l16) * LDK + quad * 8]);
            const v8s v1 = *(const v8s*)(&Vl[(dt * 16 + l16) * LDK + 32 + quad * 8]);
            v4f acc = Ofr[dt];
            acc = __builtin_amdgcn_mfma_f32_16x16x32_bf16(p0, v0, acc, 0, 0, 0);
            acc = __builtin_amdgcn_mfma_f32_16x16x32_bf16(p1, v1, acc, 0, 0, 0);
            Ofr[dt] = acc;
        }
    }

#pragma unroll
    for (int dt = 0; dt < 4; ++dt) {
#pragma unroll
        for (int r = 0; r < 4; ++r) {
            const int row = q0 + quad * 4 + r;
            const int col = h * 64 + dt * 16 + l16;
            Oout[(size_t)row * 256 + col] = Ofr[dt][r] / l_r[r];
        }
    }
}

// ---- output projection (fp32 VALU)
__global__ __launch_bounds__(256) void oproj_kernel(
    const float* __restrict__ attn, const float* __restrict__ Wo,
    const float* __restrict__ bo, float* __restrict__ out)
{
    const int n0 = blockIdx.x * 16;
    const int i = threadIdx.x;
    float acc[16];
    const float b = bo[i];
#pragma unroll
    for (int r = 0; r < 16; ++r) acc[r] = b;
#pragma unroll 4
    for (int e = 0; e < E; ++e) {
        const float w = Wo[e * 256 + i];
#pragma unroll
        for (int r = 0; r < 16; ++r)
            acc[r] = fmaf(attn[(n0 + r) * 256 + e], w, acc[r]);
    }
#pragma unroll
    for (int r = 0; r < 16; ++r)
        out[(n0 + r) * 256 + i] = acc[r];
}

extern "C" void kernel_launch(void* const* d_in, const int* in_sizes, int n_in,
                              void* d_out, int out_size, void* d_ws, size_t ws_size,
                              hipStream_t stream) {
    const float* query = (const float*)d_in[0];
    const float* key   = (const float*)d_in[1];
    const float* value = (const float*)d_in[2];
    const float* Wq    = (const float*)d_in[3];
    const float* bq    = (const float*)d_in[4];
    const float* Wk    = (const float*)d_in[5];
    const float* bk    = (const float*)d_in[6];
    const float* Wv    = (const float*)d_in[7];
    const float* bv    = (const float*)d_in[8];
    const float* Wo    = (const float*)d_in[9];
    const float* bo    = (const float*)d_in[10];
    const int*   nex   = (const int*)d_in[11];

    char* ws = (char*)d_ws;
    unsigned short* Qb = (unsigned short*)(ws);                              // 2 MB
    unsigned short* Kb = (unsigned short*)(ws + (size_t)2 * 1024 * 1024);    // 4 MB
    unsigned short* Vt = (unsigned short*)(ws + (size_t)6 * 1024 * 1024);    // 4 MB
    float* attn        = (float*)(ws + (size_t)10 * 1024 * 1024);            // 4 MB
    float* out         = (float*)d_out;

    qproj_kernel<<<256, 256, 0, stream>>>(query, Wq, bq, Qb);
    kproj_kernel<<<256, 256, 0, stream>>>(key, Wk, bk, Kb, nex);
    vproj_kernel<<<256, 256, 0, stream>>>(value, Wv, bv, Vt);
    attn_kernel<<<256, 256, 0, stream>>>(Qb, Kb, Vt, attn);
    oproj_kernel<<<256, 256, 0, stream>>>(attn, Wo, bo, out);
}

// Round 2
// 282.189 us; speedup vs baseline: 1.3680x; 1.3680x over previous
//
#include <hip/hip_runtime.h>

#define H 4
#define NQ 4096
#define NK 8192
#define D 64
#define E 256
#define BK 64
#define LDK 72
#define NSPLIT 4
#define KSPAN (NK / NSPLIT)

typedef short v8s __attribute__((ext_vector_type(8)));
typedef float v4f __attribute__((ext_vector_type(4)));

// 0.125 (1/sqrt(64)) * log2(e): scores emerge in log2 domain
#define QSCALE 0.1803368801111204f

static __device__ __forceinline__ unsigned short f2bf(float f) {
    unsigned int u = __float_as_uint(f);
    u = (u + 0x7FFFu + ((u >> 16) & 1u)) >> 16;
    return (unsigned short)u;
}

// ---- Q projection + RoPE + scale -> bf16 [H][NQ][D]
__global__ __launch_bounds__(256) void qproj_kernel(
    const float* __restrict__ query, const float* __restrict__ Wq,
    const float* __restrict__ bq, unsigned short* __restrict__ Qb)
{
    const int n0 = blockIdx.x * 8;
    const int i = threadIdx.x;
    float acc[8];
    const float b = bq[i];
#pragma unroll
    for (int r = 0; r < 8; ++r) acc[r] = b;
    for (int e = 0; e < E; e += 4) {
        const float w0 = Wq[(e + 0) * 256 + i];
        const float w1 = Wq[(e + 1) * 256 + i];
        const float w2 = Wq[(e + 2) * 256 + i];
        const float w3 = Wq[(e + 3) * 256 + i];
#pragma unroll
        for (int r = 0; r < 8; ++r) {
            const float4 x = *(const float4*)(query + (n0 + r) * 256 + e);
            acc[r] = fmaf(x.x, w0, fmaf(x.y, w1, fmaf(x.z, w2, fmaf(x.w, w3, acc[r]))));
        }
    }
    const int d = i & 63, h = i >> 6;
    const int j = d >> 1;
    const float freq = exp2f(-(float)(j & 15) * 1.66096404744368f); // 10000^(-(j%16)/8)
    const bool isx = (j < 16);
    const bool odd = (d & 1);
#pragma unroll
    for (int r = 0; r < 8; ++r) {
        const int p = n0 + r;
        const float tpos = isx ? (float)(p & 63) : (float)(p >> 6);
        const float ang = tpos * freq;
        const float c = cosf(ang), s = sinf(ang);
        const float x = acc[r];
        const float xp = __shfl_xor(x, 1, 64);
        float y = odd ? fmaf(x, c, xp * s) : fmaf(x, c, -xp * s);
        y *= QSCALE;
        Qb[(h * NQ + p) * D + d] = f2bf(y);
    }
}

// ---- K projection + conditional RoPE -> bf16 [H][NK][D]
__global__ __launch_bounds__(256) void kproj_kernel(
    const float* __restrict__ key, const float* __restrict__ Wk,
    const float* __restrict__ bk, unsigned short* __restrict__ Kb,
    const int* __restrict__ nexp)
{
    const int n0 = blockIdx.x * 16;
    const int i = threadIdx.x;
    const int nro = NK - *nexp;
    float acc[16];
    const float b = bk[i];
#pragma unroll
    for (int r = 0; r < 16; ++r) acc[r] = b;
    for (int e = 0; e < 64; e += 4) {
        const float w0 = Wk[(e + 0) * 256 + i];
        const float w1 = Wk[(e + 1) * 256 + i];
        const float w2 = Wk[(e + 2) * 256 + i];
        const float w3 = Wk[(e + 3) * 256 + i];
#pragma unroll
        for (int r = 0; r < 16; ++r) {
            const float4 x = *(const float4*)(key + (n0 + r) * 64 + e);
            acc[r] = fmaf(x.x, w0, fmaf(x.y, w1, fmaf(x.z, w2, fmaf(x.w, w3, acc[r]))));
        }
    }
    const int d = i & 63, h = i >> 6;
    const int j = d >> 1;
    const float freq = exp2f(-(float)(j & 15) * 1.66096404744368f);
    const bool isx = (j < 16);
    const bool odd = (d & 1);
#pragma unroll
    for (int r = 0; r < 16; ++r) {
        const int p = n0 + r;
        const int pc = p & 4095;
        const float tpos = isx ? (float)(pc & 63) : (float)(pc >> 6);
        const float ang = tpos * freq;
        const float c = cosf(ang), s = sinf(ang);
        const float x = acc[r];
        const float xp = __shfl_xor(x, 1, 64);
        const float yr = odd ? fmaf(x, c, xp * s) : fmaf(x, c, -xp * s);
        const float y = (p < nro) ? yr : x;
        Kb[(h * NK + p) * D + d] = f2bf(y);
    }
}

// ---- V projection -> bf16 TRANSPOSED [H][D][NK]
__global__ __launch_bounds__(256) void vproj_kernel(
    const float* __restrict__ value, const float* __restrict__ Wv,
    const float* __restrict__ bv, unsigned short* __restrict__ Vt)
{
    const int n0 = blockIdx.x * 16;
    const int i = threadIdx.x;
    float acc[16];
    const float b = bv[i];
#pragma unroll
    for (int r = 0; r < 16; ++r) acc[r] = b;
    for (int e = 0; e < 64; e += 4) {
        const float w0 = Wv[(e + 0) * 256 + i];
        const float w1 = Wv[(e + 1) * 256 + i];
        const float w2 = Wv[(e + 2) * 256 + i];
        const float w3 = Wv[(e + 3) * 256 + i];
#pragma unroll
        for (int r = 0; r < 16; ++r) {
            const float4 x = *(const float4*)(value + (n0 + r) * 64 + e);
            acc[r] = fmaf(x.x, w0, fmaf(x.y, w1, fmaf(x.z, w2, fmaf(x.w, w3, acc[r]))));
        }
    }
    const int d = i & 63, h = i >> 6;
    unsigned int buf[8];
#pragma unroll
    for (int m = 0; m < 8; ++m)
        buf[m] = (unsigned int)f2bf(acc[2 * m]) | ((unsigned int)f2bf(acc[2 * m + 1]) << 16);
    unsigned short* dst = Vt + (size_t)(h * D + d) * NK + n0;
#pragma unroll
    for (int g = 0; g < 2; ++g) {
        uint4 t4;
        t4.x = buf[4 * g]; t4.y = buf[4 * g + 1]; t4.z = buf[4 * g + 2]; t4.w = buf[4 * g + 3];
        *(uint4*)(dst + g * 8) = t4;
    }
}

// ---- flash attention partial, split-K: 1024 blocks = H(4) x qtile(64) x split(4)
// each block: 64 Q rows x KSPAN keys; emits unnormalized O + (m,l) per row
__global__ __launch_bounds__(256) void attn_part_kernel(
    const unsigned short* __restrict__ Qb, const unsigned short* __restrict__ Kb,
    const unsigned short* __restrict__ Vt, float* __restrict__ Opart,
    float2* __restrict__ ML)
{
    __shared__ alignas(16) unsigned short Kl[BK * LDK];
    __shared__ alignas(16) unsigned short Vl[D * LDK];
    __shared__ alignas(16) unsigned short Pl[4 * 16 * LDK];

    const int blk = blockIdx.x;
    const int s = blk & 3;
    const int qt = (blk >> 2) & 63;
    const int h = blk >> 8;
    const int t = threadIdx.x;
    const int w = t >> 6, lane = t & 63;
    const int quad = lane >> 4, l16 = lane & 15;

    const int q0 = qt * 64 + w * 16;
    const unsigned short* qrow = Qb + (size_t)(h * NQ + q0 + l16) * D;
    const v8s a0 = *(const v8s*)(qrow + quad * 8);
    const v8s a1 = *(const v8s*)(qrow + 32 + quad * 8);

    v4f Ofr[4];
#pragma unroll
    for (int dt = 0; dt < 4; ++dt) Ofr[dt] = v4f{0.f, 0.f, 0.f, 0.f};
    float m_r[4], l_r[4];
#pragma unroll
    for (int r = 0; r < 4; ++r) { m_r[r] = -1e30f; l_r[r] = 0.f; }

    unsigned short* Pw = &Pl[w * 16 * LDK];
    const unsigned short* Kbase = Kb + (size_t)h * NK * D;
    const unsigned short* Vbase = Vt + (size_t)h * D * NK;
    const int k_beg = s * KSPAN, k_end = k_beg + KSPAN;

    for (int k0 = k_beg; k0 < k_end; k0 += BK) {
        __syncthreads();
#pragma unroll
        for (int it = 0; it < 2; ++it) {
            const int si = t + it * 256;
            const int row = si >> 3, seg = si & 7;
            *(uint4*)(&Kl[row * LDK + seg * 8]) =
                *(const uint4*)(Kbase + (size_t)(k0 + row) * D + seg * 8);
            *(uint4*)(&Vl[row * LDK + seg * 8]) =
                *(const uint4*)(Vbase + (size_t)row * NK + k0 + seg * 8);
        }
        __syncthreads();

        v4f S[4];
#pragma unroll
        for (int tt = 0; tt < 4; ++tt) {
            const v8s b0 = *(const v8s*)(&Kl[(tt * 16 + l16) * LDK + quad * 8]);
            const v8s b1 = *(const v8s*)(&Kl[(tt * 16 + l16) * LDK + 32 + quad * 8]);
            v4f acc = v4f{0.f, 0.f, 0.f, 0.f};
            acc = __builtin_amdgcn_mfma_f32_16x16x32_bf16(a0, b0, acc, 0, 0, 0);
            acc = __builtin_amdgcn_mfma_f32_16x16x32_bf16(a1, b1, acc, 0, 0, 0);
            S[tt] = acc;
        }

        float alpha[4];
#pragma unroll
        for (int r = 0; r < 4; ++r) {
            float v = fmaxf(fmaxf(S[0][r], S[1][r]), fmaxf(S[2][r], S[3][r]));
            v = fmaxf(v, __shfl_xor(v, 1, 64));
            v = fmaxf(v, __shfl_xor(v, 2, 64));
            v = fmaxf(v, __shfl_xor(v, 4, 64));
            v = fmaxf(v, __shfl_xor(v, 8, 64));
            const float mnew = fmaxf(m_r[r], v);
            alpha[r] = __builtin_amdgcn_exp2f(m_r[r] - mnew);
            m_r[r] = mnew;
        }
        float psum[4] = {0.f, 0.f, 0.f, 0.f};
#pragma unroll
        for (int tt = 0; tt < 4; ++tt) {
#pragma unroll
            for (int r = 0; r < 4; ++r) {
                const float e = __builtin_amdgcn_exp2f(S[tt][r] - m_r[r]);
                psum[r] += e;
                Pw[(quad * 4 + r) * LDK + tt * 16 + l16] = f2bf(e);
            }
        }
#pragma unroll
        for (int r = 0; r < 4; ++r) {
            float v = psum[r];
            v += __shfl_xor(v, 1, 64);
            v += __shfl_xor(v, 2, 64);
            v += __shfl_xor(v, 4, 64);
            v += __shfl_xor(v, 8, 64);
            l_r[r] = l_r[r] * alpha[r] + v;
#pragma unroll
            for (int dt = 0; dt < 4; ++dt) Ofr[dt][r] *= alpha[r];
        }
        __asm__ volatile("s_waitcnt lgkmcnt(0)" ::: "memory");
        const v8s p0 = *(const v8s*)(&Pw[l16 * LDK + quad * 8]);
        const v8s p1 = *(const v8s*)(&Pw[l16 * LDK + 32 + quad * 8]);
#pragma unroll
        for (int dt = 0; dt < 4; ++dt) {
            const v8s v0 = *(const v8s*)(&Vl[(dt * 16 + l16) * LDK + quad * 8]);
            const v8s v1 = *(const v8s*)(&Vl[(dt * 16 + l16) * LDK + 32 + quad * 8]);
            v4f acc = Ofr[dt];
            acc = __builtin_amdgcn_mfma_f32_16x16x32_bf16(p0, v0, acc, 0, 0, 0);
            acc = __builtin_amdgcn_mfma_f32_16x16x32_bf16(p1, v1, acc, 0, 0, 0);
            Ofr[dt] = acc;
        }
    }

    float* Ob = Opart + (size_t)blk * 4096;
#pragma unroll
    for (int dt = 0; dt < 4; ++dt) {
#pragma unroll
        for (int r = 0; r < 4; ++r) {
            const int rloc = w * 16 + quad * 4 + r;
            Ob[rloc * 64 + dt * 16 + l16] = Ofr[dt][r];
        }
    }
    if (l16 == 0) {
#pragma unroll
        for (int r = 0; r < 4; ++r) {
            const int rloc = w * 16 + quad * 4 + r;
            ML[blk * 64 + rloc] = make_float2(m_r[r], l_r[r]);
        }
    }
}

// ---- combine split-K partials -> attn [NQ][256]
__global__ __launch_bounds__(256) void combine_kernel(
    const float* __restrict__ Opart, const float2* __restrict__ ML,
    float* __restrict__ attn)
{
    const int n0 = blockIdx.x * 16;
    const int i = threadIdx.x;
    const int h = i >> 6, d = i & 63;
#pragma unroll 1
    for (int r = 0; r < 16; ++r) {
        const int row = n0 + r;
        const int qt = row >> 6, rl = row & 63;
        const int b0 = (h * 64 + qt) * 4;
        float2 ml0 = ML[(b0 + 0) * 64 + rl];
        float2 ml1 = ML[(b0 + 1) * 64 + rl];
        float2 ml2 = ML[(b0 + 2) * 64 + rl];
        float2 ml3 = ML[(b0 + 3) * 64 + rl];
        const float mmax = fmaxf(fmaxf(ml0.x, ml1.x), fmaxf(ml2.x, ml3.x));
        const float w0 = __builtin_amdgcn_exp2f(ml0.x - mmax);
        const float w1 = __builtin_amdgcn_exp2f(ml1.x - mmax);
        const float w2 = __builtin_amdgcn_exp2f(ml2.x - mmax);
        const float w3 = __builtin_amdgcn_exp2f(ml3.x - mmax);
        const float l = w0 * ml0.y + w1 * ml1.y + w2 * ml2.y + w3 * ml3.y;
        const float o0 = Opart[(size_t)(b0 + 0) * 4096 + rl * 64 + d];
        const float o1 = Opart[(size_t)(b0 + 1) * 4096 + rl * 64 + d];
        const float o2 = Opart[(size_t)(b0 + 2) * 4096 + rl * 64 + d];
        const float o3 = Opart[(size_t)(b0 + 3) * 4096 + rl * 64 + d];
        const float O = fmaf(o0, w0, fmaf(o1, w1, fmaf(o2, w2, o3 * w3)));
        attn[(size_t)row * 256 + i] = O / l;
    }
}

// ---- output projection (fp32 VALU)
__global__ __launch_bounds__(256) void oproj_kernel(
    const float* __restrict__ attn, const float* __restrict__ Wo,
    const float* __restrict__ bo, float* __restrict__ out)
{
    const int n0 = blockIdx.x * 8;
    const int i = threadIdx.x;
    float acc[8];
    const float b = bo[i];
#pragma unroll
    for (int r = 0; r < 8; ++r) acc[r] = b;
    for (int e = 0; e < E; e += 4) {
        const float w0 = Wo[(e + 0) * 256 + i];
        const float w1 = Wo[(e + 1) * 256 + i];
        const float w2 = Wo[(e + 2) * 256 + i];
        const float w3 = Wo[(e + 3) * 256 + i];
#pragma unroll
        for (int r = 0; r < 8; ++r) {
            const float4 x = *(const float4*)(attn + (n0 + r) * 256 + e);
            acc[r] = fmaf(x.x, w0, fmaf(x.y, w1, fmaf(x.z, w2, fmaf(x.w, w3, acc[r]))));
        }
    }
#pragma unroll
    for (int r = 0; r < 8; ++r)
        out[(n0 + r) * 256 + i] = acc[r];
}

extern "C" void kernel_launch(void* const* d_in, const int* in_sizes, int n_in,
                              void* d_out, int out_size, void* d_ws, size_t ws_size,
                              hipStream_t stream) {
    const float* query = (const float*)d_in[0];
    const float* key   = (const float*)d_in[1];
    const float* value = (const float*)d_in[2];
    const float* Wq    = (const float*)d_in[3];
    const float* bq    = (const float*)d_in[4];
    const float* Wk    = (const float*)d_in[5];
    const float* bk    = (const float*)d_in[6];
    const float* Wv    = (const float*)d_in[7];
    const float* bv    = (const float*)d_in[8];
    const float* Wo    = (const float*)d_in[9];
    const float* bo    = (const float*)d_in[10];
    const int*   nex   = (const int*)d_in[11];

    char* ws = (char*)d_ws;
    unsigned short* Qb = (unsigned short*)(ws);                               // 2 MB
    unsigned short* Kb = (unsigned short*)(ws + (size_t)2  * 1024 * 1024);    // 4 MB
    unsigned short* Vt = (unsigned short*)(ws + (size_t)6  * 1024 * 1024);    // 4 MB
    float* Opart       = (float*)(ws + (size_t)10 * 1024 * 1024);             // 16 MB
    float2* ML         = (float2*)(ws + (size_t)26 * 1024 * 1024);            // 0.5 MB
    float* attn        = (float*)(ws + (size_t)27 * 1024 * 1024);             // 4 MB
    float* out         = (float*)d_out;

    qproj_kernel<<<512, 256, 0, stream>>>(query, Wq, bq, Qb);
    kproj_kernel<<<512, 256, 0, stream>>>(key, Wk, bk, Kb, nex);
    vproj_kernel<<<512, 256, 0, stream>>>(value, Wv, bv, Vt);
    attn_part_kernel<<<1024, 256, 0, stream>>>(Qb, Kb, Vt, Opart, ML);
    combine_kernel<<<256, 256, 0, stream>>>(Opart, ML, attn);
    oproj_kernel<<<512, 256, 0, stream>>>(attn, Wo, bo, out);
}

// Round 3
// 203.766 us; speedup vs baseline: 1.8945x; 1.3849x over previous
//
#include <hip/hip_runtime.h>

#define H 4
#define NQ 4096
#define NK 8192
#define D 64
#define BK 64
#define LDK 80
#define NSPLIT 4
#define KSPAN (NK / NSPLIT)

typedef short v8s __attribute__((ext_vector_type(8)));
typedef float v4f __attribute__((ext_vector_type(4)));

// 0.125 (1/sqrt(64)) * log2(e): scores emerge in log2 domain
#define QSCALE 0.1803368801111204f

static __device__ __forceinline__ unsigned short f2bf(float f) {
    unsigned int u = __float_as_uint(f);
    u = (u + 0x7FFFu + ((u >> 16) & 1u)) >> 16;
    return (unsigned short)u;
}
static __device__ __forceinline__ float bf2f(unsigned short h) {
    return __uint_as_float(((unsigned int)h) << 16);
}
static __device__ __forceinline__ void split8(const float* a, v8s& hi, v8s& lo) {
#pragma unroll
    for (int j = 0; j < 8; ++j) {
        unsigned short h = f2bf(a[j]);
        hi[j] = (short)h;
        lo[j] = (short)f2bf(a[j] - bf2f(h));
    }
}

// ---- W prep: bf16 hi/lo planes, TRANSPOSED [col][k]
__global__ __launch_bounds__(256) void wprep_kernel(
    const float* __restrict__ Wq, const float* __restrict__ Wk,
    const float* __restrict__ Wv, const float* __restrict__ Wo,
    unsigned short* __restrict__ Wqt, unsigned short* __restrict__ Wkt,
    unsigned short* __restrict__ Wvt, unsigned short* __restrict__ Wot)
{
    int i = blockIdx.x * 256 + threadIdx.x;
    const float* src; unsigned short* dst; int idx, sh;
    if (i < 65536)       { src = Wq; dst = Wqt; idx = i;          sh = 8; }
    else if (i < 81920)  { src = Wk; dst = Wkt; idx = i - 65536;  sh = 6; }
    else if (i < 98304)  { src = Wv; dst = Wvt; idx = i - 81920;  sh = 6; }
    else                 { src = Wo; dst = Wot; idx = i - 98304;  sh = 8; }
    const int K = 1 << sh;
    const int c = idx >> sh, e = idx & (K - 1);
    const float v = src[e * 256 + c];
    const unsigned short h = f2bf(v);
    dst[idx] = h;
    dst[idx + (K << 8)] = f2bf(v - bf2f(h));
}

// ---- Q projection (MFMA) + RoPE + scale -> bf16 [H][NQ][64]
__global__ __launch_bounds__(256) void qproj_kernel(
    const float* __restrict__ query, const unsigned short* __restrict__ Wt,
    const float* __restrict__ bq, unsigned short* __restrict__ Qb)
{
    const int n0 = blockIdx.x * 16;
    const int t = threadIdx.x, w = t >> 6, lane = t & 63;
    const int quad = lane >> 4, l16 = lane & 15;
    v4f acc[4];
#pragma unroll
    for (int ct = 0; ct < 4; ++ct) {
        const float b = bq[w * 64 + ct * 16 + l16];
        acc[ct] = v4f{b, b, b, b};
    }
    const float* arow = query + (size_t)(n0 + l16) * 256;
#pragma unroll
    for (int k0 = 0; k0 < 256; k0 += 32) {
        float av[8];
        *(float4*)av = *(const float4*)(arow + k0 + quad * 8);
        *(float4*)(av + 4) = *(const float4*)(arow + k0 + quad * 8 + 4);
        v8s ah, al;
        split8(av, ah, al);
#pragma unroll
        for (int ct = 0; ct < 4; ++ct) {
            const unsigned short* wp = Wt + (size_t)(w * 64 + ct * 16 + l16) * 256 + k0 + quad * 8;
            const v8s wh = *(const v8s*)wp;
            const v8s wl = *(const v8s*)(wp + 65536);
            acc[ct] = __builtin_amdgcn_mfma_f32_16x16x32_bf16(al, wh, acc[ct], 0, 0, 0);
            acc[ct] = __builtin_amdgcn_mfma_f32_16x16x32_bf16(ah, wl, acc[ct], 0, 0, 0);
            acc[ct] = __builtin_amdgcn_mfma_f32_16x16x32_bf16(ah, wh, acc[ct], 0, 0, 0);
        }
    }
#pragma unroll
    for (int ct = 0; ct < 4; ++ct) {
        const int d = ct * 16 + l16;
        const int j = d >> 1;
        const float freq = exp2f(-(float)(j & 15) * 1.66096404744368f);
        const bool isx = (j < 16);
        const bool odd = (d & 1);
#pragma unroll
        for (int r = 0; r < 4; ++r) {
            const int p = n0 + quad * 4 + r;
            const float tpos = isx ? (float)(p & 63) : (float)(p >> 6);
            float s, c;
            __sincosf(tpos * freq, &s, &c);
            const float x = acc[ct][r];
            const float xp = __shfl_xor(x, 1, 64);
            const float y = odd ? fmaf(x, c, xp * s) : fmaf(x, c, -xp * s);
            Qb[((size_t)(w * NQ + p) << 6) + d] = f2bf(y * QSCALE);
        }
    }
}

// ---- K projection (MFMA) + conditional RoPE -> bf16 [H][NK][64]
__global__ __launch_bounds__(256) void kproj_kernel(
    const float* __restrict__ key, const unsigned short* __restrict__ Wt,
    const float* __restrict__ bk, unsigned short* __restrict__ Kb,
    const int* __restrict__ nexp)
{
    const int n0 = blockIdx.x * 16;
    const int t = threadIdx.x, w = t >> 6, lane = t & 63;
    const int quad = lane >> 4, l16 = lane & 15;
    const int nro = NK - *nexp;
    v4f acc[4];
#pragma unroll
    for (int ct = 0; ct < 4; ++ct) {
        const float b = bk[w * 64 + ct * 16 + l16];
        acc[ct] = v4f{b, b, b, b};
    }
    const float* arow = key + (size_t)(n0 + l16) * 64;
#pragma unroll
    for (int k0 = 0; k0 < 64; k0 += 32) {
        float av[8];
        *(float4*)av = *(const float4*)(arow + k0 + quad * 8);
        *(float4*)(av + 4) = *(const float4*)(arow + k0 + quad * 8 + 4);
        v8s ah, al;
        split8(av, ah, al);
#pragma unroll
        for (int ct = 0; ct < 4; ++ct) {
            const unsigned short* wp = Wt + (size_t)(w * 64 + ct * 16 + l16) * 64 + k0 + quad * 8;
            const v8s wh = *(const v8s*)wp;
            const v8s wl = *(const v8s*)(wp + 16384);
            acc[ct] = __builtin_amdgcn_mfma_f32_16x16x32_bf16(al, wh, acc[ct], 0, 0, 0);
            acc[ct] = __builtin_amdgcn_mfma_f32_16x16x32_bf16(ah, wl, acc[ct], 0, 0, 0);
            acc[ct] = __builtin_amdgcn_mfma_f32_16x16x32_bf16(ah, wh, acc[ct], 0, 0, 0);
        }
    }
#pragma unroll
    for (int ct = 0; ct < 4; ++ct) {
        const int d = ct * 16 + l16;
        const int j = d >> 1;
        const float freq = exp2f(-(float)(j & 15) * 1.66096404744368f);
        const bool isx = (j < 16);
        const bool odd = (d & 1);
#pragma unroll
        for (int r = 0; r < 4; ++r) {
            const int p = n0 + quad * 4 + r;
            const int pc = p & 4095;
            const float tpos = isx ? (float)(pc & 63) : (float)(pc >> 6);
            float s, c;
            __sincosf(tpos * freq, &s, &c);
            const float x = acc[ct][r];
            const float xp = __shfl_xor(x, 1, 64);
            float y = odd ? fmaf(x, c, xp * s) : fmaf(x, c, -xp * s);
            y = (p < nro) ? y : x;
            Kb[((size_t)(w * NK + p) << 6) + d] = f2bf(y);
        }
    }
}

// ---- V projection (MFMA) -> bf16 TRANSPOSED [H*64][NK]
__global__ __launch_bounds__(256) void vproj_kernel(
    const float* __restrict__ value, const unsigned short* __restrict__ Wt,
    const float* __restrict__ bv, unsigned short* __restrict__ Vt)
{
    const int n0 = blockIdx.x * 16;
    const int t = threadIdx.x, w = t >> 6, lane = t & 63;
    const int quad = lane >> 4, l16 = lane & 15;
    v4f acc[4];
#pragma unroll
    for (int ct = 0; ct < 4; ++ct) {
        const float b = bv[w * 64 + ct * 16 + l16];
        acc[ct] = v4f{b, b, b, b};
    }
    const float* arow = value + (size_t)(n0 + l16) * 64;
#pragma unroll
    for (int k0 = 0; k0 < 64; k0 += 32) {
        float av[8];
        *(float4*)av = *(const float4*)(arow + k0 + quad * 8);
        *(float4*)(av + 4) = *(const float4*)(arow + k0 + quad * 8 + 4);
        v8s ah, al;
        split8(av, ah, al);
#pragma unroll
        for (int ct = 0; ct < 4; ++ct) {
            const unsigned short* wp = Wt + (size_t)(w * 64 + ct * 16 + l16) * 64 + k0 + quad * 8;
            const v8s wh = *(const v8s*)wp;
            const v8s wl = *(const v8s*)(wp + 16384);
            acc[ct] = __builtin_amdgcn_mfma_f32_16x16x32_bf16(al, wh, acc[ct], 0, 0, 0);
            acc[ct] = __builtin_amdgcn_mfma_f32_16x16x32_bf16(ah, wl, acc[ct], 0, 0, 0);
            acc[ct] = __builtin_amdgcn_mfma_f32_16x16x32_bf16(ah, wh, acc[ct], 0, 0, 0);
        }
    }
#pragma unroll
    for (int ct = 0; ct < 4; ++ct) {
        uint2 u;
        u.x = (unsigned int)f2bf(acc[ct][0]) | ((unsigned int)f2bf(acc[ct][1]) << 16);
        u.y = (unsigned int)f2bf(acc[ct][2]) | ((unsigned int)f2bf(acc[ct][3]) << 16);
        *(uint2*)(Vt + (size_t)(w * 64 + ct * 16 + l16) * NK + n0 + quad * 4) = u;
    }
}

// ---- flash attention partial, split-K, S^T formulation
// 1024 blocks = H(4) x qtile(64) x split(4); 4 waves x 16 q-rows
__global__ __launch_bounds__(256) void attn_part_kernel(
    const unsigned short* __restrict__ Qb, const unsigned short* __restrict__ Kb,
    const unsigned short* __restrict__ Vt, float* __restrict__ Opart,
    float2* __restrict__ ML)
{
    __shared__ alignas(16) unsigned short Kl[BK * LDK];
    __shared__ alignas(16) unsigned short Vl[D * LDK];
    __shared__ alignas(16) unsigned short Pl[4 * 16 * LDK];

    const int blk = blockIdx.x;
    const int s = blk & 3;
    const int qt = (blk >> 2) & 63;
    const int h = blk >> 8;
    const int t = threadIdx.x;
    const int w = t >> 6, lane = t & 63;
    const int quad = lane >> 4, l16 = lane & 15;

    const int q0 = qt * 64 + w * 16;
    const unsigned short* qrow = Qb + ((size_t)(h * NQ + q0 + l16) << 6);
    const v8s qf0 = *(const v8s*)(qrow + quad * 8);
    const v8s qf1 = *(const v8s*)(qrow + 32 + quad * 8);

    v4f Ofr[4];
#pragma unroll
    for (int dt = 0; dt < 4; ++dt) Ofr[dt] = v4f{0.f, 0.f, 0.f, 0.f};
    float m_s = -1e30f, l_s = 0.f;

    unsigned short* Pw = &Pl[w * 16 * LDK];
    const unsigned short* Kbase = Kb + ((size_t)h * NK << 6);
    const unsigned short* Vbase = Vt + (size_t)h * D * NK;
    const int k_beg = s * KSPAN, k_end = k_beg + KSPAN;

    for (int k0 = k_beg; k0 < k_end; k0 += BK) {
        __syncthreads();
#pragma unroll
        for (int it = 0; it < 2; ++it) {
            const int si = t + it * 256;
            const int row = si >> 3, seg = si & 7;
            *(uint4*)(&Kl[row * LDK + seg * 8]) =
                *(const uint4*)(Kbase + ((size_t)(k0 + row) << 6) + seg * 8);
            *(uint4*)(&Vl[row * LDK + seg * 8]) =
                *(const uint4*)(Vbase + (size_t)row * NK + k0 + seg * 8);
        }
        __syncthreads();

        // S^T = K Q^T : rows = k-positions, cols = q-rows
        v4f S[4];
#pragma unroll
        for (int tt = 0; tt < 4; ++tt) {
            const v8s kf0 = *(const v8s*)(&Kl[(tt * 16 + l16) * LDK + quad * 8]);
            const v8s kf1 = *(const v8s*)(&Kl[(tt * 16 + l16) * LDK + 32 + quad * 8]);
            v4f a = v4f{0.f, 0.f, 0.f, 0.f};
            a = __builtin_amdgcn_mfma_f32_16x16x32_bf16(kf0, qf0, a, 0, 0, 0);
            a = __builtin_amdgcn_mfma_f32_16x16x32_bf16(kf1, qf1, a, 0, 0, 0);
            S[tt] = a;
        }

        // per-lane online softmax for q-row = l16 (k spread over regs + quads)
        float vmax = S[0][0];
#pragma unroll
        for (int tt = 0; tt < 4; ++tt)
#pragma unroll
            for (int r = 0; r < 4; ++r) vmax = fmaxf(vmax, S[tt][r]);
        vmax = fmaxf(vmax, __shfl_xor(vmax, 16, 64));
        vmax = fmaxf(vmax, __shfl_xor(vmax, 32, 64));
        const float mnew = fmaxf(m_s, vmax);
        const float alpha = __builtin_amdgcn_exp2f(m_s - mnew);
        m_s = mnew;

        float e[4][4];
        float ps = 0.f;
#pragma unroll
        for (int tt = 0; tt < 4; ++tt)
#pragma unroll
            for (int r = 0; r < 4; ++r) {
                e[tt][r] = __builtin_amdgcn_exp2f(S[tt][r] - mnew);
                ps += e[tt][r];
            }
        ps += __shfl_xor(ps, 16, 64);
        ps += __shfl_xor(ps, 32, 64);
        l_s = l_s * alpha + ps;

        // write P^T back transposed: [q=l16][k] -> vectorized b64
#pragma unroll
        for (int tt = 0; tt < 4; ++tt) {
            uint2 u;
            u.x = (unsigned int)f2bf(e[tt][0]) | ((unsigned int)f2bf(e[tt][1]) << 16);
            u.y = (unsigned int)f2bf(e[tt][2]) | ((unsigned int)f2bf(e[tt][3]) << 16);
            *(uint2*)(&Pw[l16 * LDK + tt * 16 + quad * 4]) = u;
        }

        // alpha for O rows (q = quad*4+r) from lane l16 = quad*4+r
        float al4[4];
#pragma unroll
        for (int r = 0; r < 4; ++r) al4[r] = __shfl(alpha, quad * 4 + r, 64);
#pragma unroll
        for (int dt = 0; dt < 4; ++dt)
#pragma unroll
            for (int r = 0; r < 4; ++r) Ofr[dt][r] *= al4[r];

        __asm__ volatile("s_waitcnt lgkmcnt(0)" ::: "memory");
        const v8s pf0 = *(const v8s*)(&Pw[l16 * LDK + quad * 8]);
        const v8s pf1 = *(const v8s*)(&Pw[l16 * LDK + 32 + quad * 8]);
#pragma unroll
        for (int dt = 0; dt < 4; ++dt) {
            const v8s vf0 = *(const v8s*)(&Vl[(dt * 16 + l16) * LDK + quad * 8]);
            const v8s vf1 = *(const v8s*)(&Vl[(dt * 16 + l16) * LDK + 32 + quad * 8]);
            v4f a = Ofr[dt];
            a = __builtin_amdgcn_mfma_f32_16x16x32_bf16(pf0, vf0, a, 0, 0, 0);
            a = __builtin_amdgcn_mfma_f32_16x16x32_bf16(pf1, vf1, a, 0, 0, 0);
            Ofr[dt] = a;
        }
    }

    float* Ob = Opart + (size_t)blk * 4096;
#pragma unroll
    for (int dt = 0; dt < 4; ++dt)
#pragma unroll
        for (int r = 0; r < 4; ++r)
            Ob[(w * 16 + quad * 4 + r) * 64 + dt * 16 + l16] = Ofr[dt][r];
    if (lane < 16)
        ML[blk * 64 + w * 16 + lane] = make_float2(m_s, l_s);
}

// ---- output projection (MFMA) with fused split-K combine
__global__ __launch_bounds__(256) void oproj_kernel(
    const float* __restrict__ Opart, const float2* __restrict__ ML,
    const unsigned short* __restrict__ Wt, const float* __restrict__ bo,
    float* __restrict__ out)
{
    const int n0 = blockIdx.x * 16;
    const int t = threadIdx.x, w = t >> 6, lane = t & 63;
    const int quad = lane >> 4, l16 = lane & 15;
    v4f acc[4];
#pragma unroll
    for (int ct = 0; ct < 4; ++ct) {
        const float b = bo[w * 64 + ct * 16 + l16];
        acc[ct] = v4f{b, b, b, b};
    }
    const int n = n0 + l16;
    const int qt = n >> 6, rl = n & 63;
#pragma unroll
    for (int hh = 0; hh < 4; ++hh) {
        const int b0 = (hh * 64 + qt) * 4;
        const float2 m0 = ML[(b0 + 0) * 64 + rl];
        const float2 m1 = ML[(b0 + 1) * 64 + rl];
        const float2 m2 = ML[(b0 + 2) * 64 + rl];
        const float2 m3 = ML[(b0 + 3) * 64 + rl];
        const float mmax = fmaxf(fmaxf(m0.x, m1.x), fmaxf(m2.x, m3.x));
        float w0 = __builtin_amdgcn_exp2f(m0.x - mmax);
        float w1 = __builtin_amdgcn_exp2f(m1.x - mmax);
        float w2 = __builtin_amdgcn_exp2f(m2.x - mmax);
        float w3 = __builtin_amdgcn_exp2f(m3.x - mmax);
        const float linv = 1.f / (w0 * m0.y + w1 * m1.y + w2 * m2.y + w3 * m3.y);
        w0 *= linv; w1 *= linv; w2 *= linv; w3 *= linv;
#pragma unroll
        for (int half = 0; half < 2; ++half) {
            const int k0 = hh * 64 + half * 32;
            const int d0 = half * 32 + quad * 8;
            const float* op0 = Opart + ((size_t)(b0 + 0)) * 4096 + rl * 64 + d0;
            const float* op1 = Opart + ((size_t)(b0 + 1)) * 4096 + rl * 64 + d0;
            const float* op2 = Opart + ((size_t)(b0 + 2)) * 4096 + rl * 64 + d0;
            const float* op3 = Opart + ((size_t)(b0 + 3)) * 4096 + rl * 64 + d0;
            float a[8];
#pragma unroll
            for (int g = 0; g < 2; ++g) {
                const float4 x0 = *(const float4*)(op0 + g * 4);
                const float4 x1 = *(const float4*)(op1 + g * 4);
                const float4 x2 = *(const float4*)(op2 + g * 4);
                const float4 x3 = *(const float4*)(op3 + g * 4);
                a[g * 4 + 0] = fmaf(x0.x, w0, fmaf(x1.x, w1, fmaf(x2.x, w2, x3.x * w3)));
                a[g * 4 + 1] = fmaf(x0.y, w0, fmaf(x1.y, w1, fmaf(x2.y, w2, x3.y * w3)));
                a[g * 4 + 2] = fmaf(x0.z, w0, fmaf(x1.z, w1, fmaf(x2.z, w2, x3.z * w3)));
                a[g * 4 + 3] = fmaf(x0.w, w0, fmaf(x1.w, w1, fmaf(x2.w, w2, x3.w * w3)));
            }
            v8s ah, al;
            split8(a, ah, al);
#pragma unroll
            for (int ct = 0; ct < 4; ++ct) {
                const unsigned short* wp = Wt + (size_t)(w * 64 + ct * 16 + l16) * 256 + k0 + quad * 8;
                const v8s whp = *(const v8s*)wp;
                const v8s wlp = *(const v8s*)(wp + 65536);
                acc[ct] = __builtin_amdgcn_mfma_f32_16x16x32_bf16(al, whp, acc[ct], 0, 0, 0);
                acc[ct] = __builtin_amdgcn_mfma_f32_16x16x32_bf16(ah, wlp, acc[ct], 0, 0, 0);
                acc[ct] = __builtin_amdgcn_mfma_f32_16x16x32_bf16(ah, whp, acc[ct], 0, 0, 0);
            }
        }
    }
#pragma unroll
    for (int ct = 0; ct < 4; ++ct)
#pragma unroll
        for (int r = 0; r < 4; ++r)
            out[(size_t)(n0 + quad * 4 + r) * 256 + w * 64 + ct * 16 + l16] = acc[ct][r];
}

extern "C" void kernel_launch(void* const* d_in, const int* in_sizes, int n_in,
                              void* d_out, int out_size, void* d_ws, size_t ws_size,
                              hipStream_t stream) {
    const float* query = (const float*)d_in[0];
    const float* key   = (const float*)d_in[1];
    const float* value = (const float*)d_in[2];
    const float* Wq    = (const float*)d_in[3];
    const float* bq    = (const float*)d_in[4];
    const float* Wk    = (const float*)d_in[5];
    const float* bk    = (const float*)d_in[6];
    const float* Wv    = (const float*)d_in[7];
    const float* bv    = (const float*)d_in[8];
    const float* Wo    = (const float*)d_in[9];
    const float* bo    = (const float*)d_in[10];
    const int*   nex   = (const int*)d_in[11];

    char* ws = (char*)d_ws;
    unsigned short* Qb  = (unsigned short*)(ws);                               // 2 MB
    unsigned short* Kb  = (unsigned short*)(ws + (size_t)2  * 1024 * 1024);    // 4 MB
    unsigned short* Vt  = (unsigned short*)(ws + (size_t)6  * 1024 * 1024);    // 4 MB
    float* Opart        = (float*)(ws + (size_t)10 * 1024 * 1024);             // 16 MB
    float2* ML          = (float2*)(ws + (size_t)26 * 1024 * 1024);            // 0.5 MB
    unsigned short* Wqt = (unsigned short*)(ws + (size_t)27 * 1024 * 1024);            // 256 KB
    unsigned short* Wkt = (unsigned short*)(ws + (size_t)27 * 1024 * 1024 + 256*1024); // 64 KB
    unsigned short* Wvt = (unsigned short*)(ws + (size_t)27 * 1024 * 1024 + 320*1024); // 64 KB
    unsigned short* Wot = (unsigned short*)(ws + (size_t)27 * 1024 * 1024 + 384*1024); // 256 KB
    float* out          = (float*)d_out;

    wprep_kernel<<<640, 256, 0, stream>>>(Wq, Wk, Wv, Wo, Wqt, Wkt, Wvt, Wot);
    qproj_kernel<<<256, 256, 0, stream>>>(query, Wqt, bq, Qb);
    kproj_kernel<<<512, 256, 0, stream>>>(key, Wkt, bk, Kb, nex);
    vproj_kernel<<<512, 256, 0, stream>>>(value, Wvt, bv, Vt);
    attn_part_kernel<<<1024, 256, 0, stream>>>(Qb, Kb, Vt, Opart, ML);
    oproj_kernel<<<256, 256, 0, stream>>>(Opart, ML, Wot, bo, out);
}